// Round 1
// baseline (3632.235 us; speedup 1.0000x reference)
//
#include <hip/hip_runtime.h>

#define T_LEN   2048
#define D_IN    15
#define NH1     60
#define NG1     240
#define NH2     30
#define NG2     120
#define XCHUNK  256
#define NTHREADS 384

__device__ __forceinline__ float fexp(float x) {
    // e^x = 2^(x*log2 e)
    return __builtin_amdgcn_exp2f(x * 1.44269504088896340736f);
}
__device__ __forceinline__ float frcp(float x) {
    return __builtin_amdgcn_rcpf(x);
}
__device__ __forceinline__ float fsigmoid(float x) {
    return frcp(1.0f + fexp(-x));
}
__device__ __forceinline__ float ftanh(float x) {
    // tanh(x) = 1 - 2/(e^{2x}+1);  e^{2x} = 2^(x * 2/ln2)
    float e = __builtin_amdgcn_exp2f(x * 2.88539008177792681472f);
    return 1.0f - 2.0f * frcp(e + 1.0f);
}

#define FMA4(vec, wb)                              \
    do {                                           \
        a0 += (vec).x * wreg[(wb) + 0];            \
        a1 += (vec).y * wreg[(wb) + 1];            \
        a2 += (vec).z * wreg[(wb) + 2];            \
        a3 += (vec).w * wreg[(wb) + 3];            \
    } while (0)

__global__ __launch_bounds__(NTHREADS, 3) void lstm_fused(
    const float* __restrict__ x,
    const float* __restrict__ Wih1, const float* __restrict__ Whh1,
    const float* __restrict__ bih1, const float* __restrict__ bhh1,
    const float* __restrict__ Wih2, const float* __restrict__ Whh2,
    const float* __restrict__ bih2, const float* __restrict__ bhh2,
    const float* __restrict__ Wp,   const float* __restrict__ bp,
    float* __restrict__ out)
{
    __shared__ __align__(16) float xls[XCHUNK * 16];  // 16 KB, row-padded 15->16
    __shared__ __align__(16) float h1ls[64];
    __shared__ __align__(16) float h2ls[32];
    __shared__ __align__(16) float g1ls[NG1];
    __shared__ __align__(16) float g2ls[NG2];

    const int tid  = threadIdx.x;
    const int b    = blockIdx.x;
    const bool isL1 = (tid < 256);      // waves 0-3 = layer1, waves 4-5 = layer2
    const int g2id = tid - 256;         // layer-2 gate id (0..119 valid)

    float wreg[92];
    float bias = 0.0f, wpv = 0.0f, bpv = 0.0f;
    float c1 = 0.0f, c2 = 0.0f;

    if (isL1) {
        if (tid < NG1) {
            #pragma unroll
            for (int k = 0; k < D_IN; ++k) wreg[k] = Wih1[tid * D_IN + k];
            wreg[15] = 0.0f;  // pad weight for 16-wide x read
            #pragma unroll
            for (int k = 0; k < NH1; ++k) wreg[16 + k] = Whh1[tid * NH1 + k];
            bias = bih1[tid] + bhh1[tid];
        }
    } else {
        if (g2id < NG2) {
            #pragma unroll
            for (int k = 0; k < NH1; ++k) wreg[k] = Wih2[g2id * NH1 + k];
            #pragma unroll
            for (int k = 0; k < NH2; ++k) wreg[60 + k] = Whh2[g2id * NH2 + k];
            wreg[90] = 0.0f;  // pad weights for 32-wide h2 read
            wreg[91] = 0.0f;
            bias = bih2[g2id] + bhh2[g2id];
        }
        if (g2id >= 0 && g2id < NH2) wpv = Wp[g2id];
        bpv = bp[0];
    }

    // zero-init recurrent state in LDS (incl. pads, which stay 0 forever)
    if (tid < 64)                 h1ls[tid] = 0.0f;
    if (tid >= 64 && tid < 96)    h2ls[tid - 64] = 0.0f;
    __syncthreads();

    const float* xbase = x + (size_t)b * T_LEN * D_IN;
    float* outb = out + (size_t)b * T_LEN;

    for (int iter = 0; iter <= T_LEN; ++iter) {
        // ---- stage next 256 timesteps of x into LDS (uniform branch) ----
        if ((iter & (XCHUNK - 1)) == 0 && iter < T_LEN) {
            const float* src = xbase + (size_t)iter * D_IN;
            #pragma unroll
            for (int r = 0; r < (XCHUNK * D_IN) / NTHREADS; ++r) {
                int i = tid + r * NTHREADS;          // 0..3839, exact
                int tt = i / D_IN;
                int dd = i - tt * D_IN;
                xls[tt * 16 + dd] = src[i];
            }
            __syncthreads();
        }

        // ---------------- phase 1: gate pre-activations ----------------
        if (isL1) {
            if (tid < NG1 && iter < T_LEN) {
                const float4* xv = (const float4*)(xls + (iter & (XCHUNK - 1)) * 16);
                const float4* hv = (const float4*)h1ls;
                float a0 = bias, a1 = 0.0f, a2 = 0.0f, a3 = 0.0f;
                #pragma unroll
                for (int k = 0; k < 4; ++k) { float4 v = xv[k]; FMA4(v, 4 * k); }
                #pragma unroll
                for (int k = 0; k < 15; ++k) { float4 v = hv[k]; FMA4(v, 16 + 4 * k); }
                float acc = (a0 + a1) + (a2 + a3);
                float act = (tid >= 120 && tid < 180) ? ftanh(acc) : fsigmoid(acc);
                g1ls[tid] = act;
            }
        } else {
            if (g2id < NG2 && iter >= 1) {
                const float4* hv  = (const float4*)h1ls;
                const float4* h2v = (const float4*)h2ls;
                float a0 = bias, a1 = 0.0f, a2 = 0.0f, a3 = 0.0f;
                #pragma unroll
                for (int k = 0; k < 15; ++k) { float4 v = hv[k];  FMA4(v, 4 * k); }
                #pragma unroll
                for (int k = 0; k < 8; ++k)  { float4 v = h2v[k]; FMA4(v, 60 + 4 * k); }
                float acc = (a0 + a1) + (a2 + a3);
                float act = (g2id >= 60 && g2id < 90) ? ftanh(acc) : fsigmoid(acc);
                g2ls[g2id] = act;
            }
        }
        __syncthreads();

        // ---------------- phase 2: state update ----------------
        if (isL1) {
            if (tid < NH1 && iter < T_LEN) {
                float gi = g1ls[tid];
                float gf = g1ls[60 + tid];
                float gg = g1ls[120 + tid];
                float go = g1ls[180 + tid];
                c1 = gf * c1 + gi * gg;
                h1ls[tid] = go * ftanh(c1);
            }
        } else {
            if (g2id < 32 && iter >= 1) {
                float p = 0.0f;
                if (g2id < NH2) {
                    float gi = g2ls[g2id];
                    float gf = g2ls[30 + g2id];
                    float gg = g2ls[60 + g2id];
                    float go = g2ls[90 + g2id];
                    c2 = gf * c2 + gi * gg;
                    float h2v = go * ftanh(c2);
                    h2ls[g2id] = h2v;
                    p = h2v * wpv;
                }
                #pragma unroll
                for (int off = 16; off > 0; off >>= 1)
                    p += __shfl_down(p, off, 32);
                if (g2id == 0) outb[iter - 1] = p + bpv;
            }
        }
        __syncthreads();
    }
}

extern "C" void kernel_launch(void* const* d_in, const int* in_sizes, int n_in,
                              void* d_out, int out_size, void* d_ws, size_t ws_size,
                              hipStream_t stream) {
    const float* x    = (const float*)d_in[0];
    const float* Wih1 = (const float*)d_in[1];
    const float* Whh1 = (const float*)d_in[2];
    const float* bih1 = (const float*)d_in[3];
    const float* bhh1 = (const float*)d_in[4];
    const float* Wih2 = (const float*)d_in[5];
    const float* Whh2 = (const float*)d_in[6];
    const float* bih2 = (const float*)d_in[7];
    const float* bhh2 = (const float*)d_in[8];
    const float* Wp   = (const float*)d_in[9];
    const float* bp   = (const float*)d_in[10];

    int B = in_sizes[0] / (T_LEN * D_IN);   // 512

    lstm_fused<<<B, NTHREADS, 0, stream>>>(x, Wih1, Whh1, bih1, bhh1,
                                           Wih2, Whh2, bih2, bhh2,
                                           Wp, bp, (float*)d_out);
}

// Round 2
// 2954.667 us; speedup vs baseline: 1.2293x; 1.2293x over previous
//
#include <hip/hip_runtime.h>

#define T_LEN   2048
#define D_IN    15
#define XCHUNK  256
#define NTHREADS 384

__device__ __forceinline__ float fexp(float x) {
    return __builtin_amdgcn_exp2f(x * 1.44269504088896340736f);
}
__device__ __forceinline__ float frcp(float x) {
    return __builtin_amdgcn_rcpf(x);
}
__device__ __forceinline__ float fsigmoid(float x) {
    return frcp(1.0f + fexp(-x));
}
__device__ __forceinline__ float ftanh(float x) {
    float e = __builtin_amdgcn_exp2f(x * 2.88539008177792681472f);
    return 1.0f - 2.0f * frcp(e + 1.0f);
}

#define STEP(vv, ww) do { a0 += (vv).x*(ww).x; a1 += (vv).y*(ww).y; \
                          a2 += (vv).z*(ww).z; a3 += (vv).w*(ww).w; } while (0)

__global__ __launch_bounds__(NTHREADS, 3) void lstm_fused(
    const float* __restrict__ x,
    const float* __restrict__ Wih1, const float* __restrict__ Whh1,
    const float* __restrict__ bih1, const float* __restrict__ bhh1,
    const float* __restrict__ Wih2, const float* __restrict__ Whh2,
    const float* __restrict__ bih2, const float* __restrict__ bhh2,
    const float* __restrict__ Wp,   const float* __restrict__ bp,
    float* __restrict__ out)
{
    __shared__ __align__(16) float xls[XCHUNK * 16];   // 16 KB, rows padded 15->16
    __shared__ __align__(16) float h1buf[2][64];       // double-buffered h1 (60 used)
    __shared__ __align__(16) float h2buf[2][32];       // double-buffered h2 (30 used, 30..31 = 0)
    __shared__ __align__(16) float g1ls[240];
    __shared__ __align__(16) float g2ls[120];
    __shared__ float ring[30 * 65];                    // h2 history, stride 65 = conflict-free
    __shared__ float wpls[32];

    const int tid  = threadIdx.x;
    const int b    = blockIdx.x;
    const bool isL1 = (tid < 256);        // waves 0-3 = layer1, waves 4-5 = layer2
    const int g2id = tid - 256;

    // ---- per-lane weights in NAMED float4 registers (no array => no scratch demotion)
    float4 z4 = make_float4(0.f, 0.f, 0.f, 0.f);
    float4 w0=z4,w1=z4,w2=z4,w3=z4,w4=z4,w5=z4,w6=z4,w7=z4,w8=z4,w9=z4,w10=z4,
           w11=z4,w12=z4,w13=z4,w14=z4,w15=z4,w16=z4,w17=z4,w18=z4,w19=z4,w20=z4,
           w21=z4,w22=z4;

    float bias = 0.0f, c1 = 0.0f, c2 = 0.0f;

    if (tid < 240) {
        const float* wi = Wih1 + tid * D_IN;           // 15 floats, unaligned -> scalar
        w0 = make_float4(wi[0],  wi[1],  wi[2],  wi[3]);
        w1 = make_float4(wi[4],  wi[5],  wi[6],  wi[7]);
        w2 = make_float4(wi[8],  wi[9],  wi[10], wi[11]);
        w3 = make_float4(wi[12], wi[13], wi[14], 0.0f);
        const float4* wh = (const float4*)(Whh1 + tid * 60);  // 240 B stride, 16B-aligned
        w4 = wh[0];  w5 = wh[1];  w6 = wh[2];  w7 = wh[3];  w8 = wh[4];
        w9 = wh[5];  w10 = wh[6]; w11 = wh[7]; w12 = wh[8]; w13 = wh[9];
        w14 = wh[10];w15 = wh[11];w16 = wh[12];w17 = wh[13];w18 = wh[14];
        bias = bih1[tid] + bhh1[tid];
    } else if (g2id < 120) {
        const float4* wa = (const float4*)(Wih2 + g2id * 60); // aligned
        w0 = wa[0];  w1 = wa[1];  w2 = wa[2];  w3 = wa[3];  w4 = wa[4];
        w5 = wa[5];  w6 = wa[6];  w7 = wa[7];  w8 = wa[8];  w9 = wa[9];
        w10 = wa[10];w11 = wa[11];w12 = wa[12];w13 = wa[13];w14 = wa[14];
        const float* wh = Whh2 + g2id * 30;            // 120 B stride, not aligned -> scalar
        w15 = make_float4(wh[0],  wh[1],  wh[2],  wh[3]);
        w16 = make_float4(wh[4],  wh[5],  wh[6],  wh[7]);
        w17 = make_float4(wh[8],  wh[9],  wh[10], wh[11]);
        w18 = make_float4(wh[12], wh[13], wh[14], wh[15]);
        w19 = make_float4(wh[16], wh[17], wh[18], wh[19]);
        w20 = make_float4(wh[20], wh[21], wh[22], wh[23]);
        w21 = make_float4(wh[24], wh[25], wh[26], wh[27]);
        w22 = make_float4(wh[28], wh[29], 0.0f,   0.0f);
        bias = bih2[g2id] + bhh2[g2id];
    }

    float bpv = bp[0];
    if (tid < 30)                 wpls[tid] = Wp[tid];
    if (tid >= 30 && tid < 32)    wpls[tid] = 0.0f;
    if (tid >= 32 && tid < 96)  { h1buf[0][tid-32] = 0.0f; h1buf[1][tid-32] = 0.0f; }
    if (tid >= 96 && tid < 128) { h2buf[0][tid-96] = 0.0f; h2buf[1][tid-96] = 0.0f; }
    __syncthreads();

    const float* xbase = x + (size_t)b * T_LEN * D_IN;
    float* outb = out + (size_t)b * T_LEN;

    for (int t = 0; t <= T_LEN; ++t) {
        const int cur = t & 1;
        const int nxt = cur ^ 1;

        // ---- stage next 256 timesteps of x into LDS (wave-uniform branch) ----
        if ((t & (XCHUNK - 1)) == 0 && t < T_LEN) {
            const float* src = xbase + (size_t)t * D_IN;
            #pragma unroll
            for (int r = 0; r < (XCHUNK * D_IN) / NTHREADS; ++r) {
                int i = tid + r * NTHREADS;            // 0..3839 exact
                int tt = i / D_IN;
                int dd = i - tt * D_IN;
                xls[tt * 16 + dd] = src[i];
            }
            if (tid < XCHUNK) xls[tid * 16 + 15] = 0.0f;   // zero the pad lane
            __syncthreads();
        }

        // ---------------- phase 1: gate pre-activations ----------------
        if (isL1) {
            if (tid < 240 && t < T_LEN) {
                const float4* xv = (const float4*)(xls + (t & (XCHUNK - 1)) * 16);
                const float4* hv = (const float4*)h1buf[cur];
                float a0 = bias, a1 = 0.f, a2 = 0.f, a3 = 0.f;
                float4 v;
                v = xv[0]; STEP(v, w0);  v = xv[1]; STEP(v, w1);
                v = xv[2]; STEP(v, w2);  v = xv[3]; STEP(v, w3);
                v = hv[0];  STEP(v, w4);  v = hv[1];  STEP(v, w5);
                v = hv[2];  STEP(v, w6);  v = hv[3];  STEP(v, w7);
                v = hv[4];  STEP(v, w8);  v = hv[5];  STEP(v, w9);
                v = hv[6];  STEP(v, w10); v = hv[7];  STEP(v, w11);
                v = hv[8];  STEP(v, w12); v = hv[9];  STEP(v, w13);
                v = hv[10]; STEP(v, w14); v = hv[11]; STEP(v, w15);
                v = hv[12]; STEP(v, w16); v = hv[13]; STEP(v, w17);
                v = hv[14]; STEP(v, w18);
                float acc = (a0 + a1) + (a2 + a3);
                g1ls[tid] = (tid >= 120 && tid < 180) ? ftanh(acc) : fsigmoid(acc);
            }
        } else {
            if (g2id < 120 && t >= 1) {
                const float4* hv  = (const float4*)h1buf[cur];
                const float4* h2v = (const float4*)h2buf[cur];
                float a0 = bias, a1 = 0.f, a2 = 0.f, a3 = 0.f;
                float4 v;
                v = hv[0];  STEP(v, w0);  v = hv[1];  STEP(v, w1);
                v = hv[2];  STEP(v, w2);  v = hv[3];  STEP(v, w3);
                v = hv[4];  STEP(v, w4);  v = hv[5];  STEP(v, w5);
                v = hv[6];  STEP(v, w6);  v = hv[7];  STEP(v, w7);
                v = hv[8];  STEP(v, w8);  v = hv[9];  STEP(v, w9);
                v = hv[10]; STEP(v, w10); v = hv[11]; STEP(v, w11);
                v = hv[12]; STEP(v, w12); v = hv[13]; STEP(v, w13);
                v = hv[14]; STEP(v, w14);
                v = h2v[0]; STEP(v, w15); v = h2v[1]; STEP(v, w16);
                v = h2v[2]; STEP(v, w17); v = h2v[3]; STEP(v, w18);
                v = h2v[4]; STEP(v, w19); v = h2v[5]; STEP(v, w20);
                v = h2v[6]; STEP(v, w21); v = h2v[7]; STEP(v, w22);
                float acc = (a0 + a1) + (a2 + a3);
                g2ls[g2id] = (g2id >= 60 && g2id < 90) ? ftanh(acc) : fsigmoid(acc);
            }
        }
        __syncthreads();   // B1: gate values visible

        // ---------------- phase 2: state update ----------------
        if (isL1) {
            if (tid < 60 && t < T_LEN) {
                float gi = g1ls[tid];
                float gf = g1ls[60 + tid];
                float gg = g1ls[120 + tid];
                float go = g1ls[180 + tid];
                c1 = gf * c1 + gi * gg;
                h1buf[nxt][tid] = go * ftanh(c1);
            }
        } else {
            if (g2id < 30 && t >= 1) {
                float gi = g2ls[g2id];
                float gf = g2ls[30 + g2id];
                float gg = g2ls[60 + g2id];
                float go = g2ls[90 + g2id];
                c2 = gf * c2 + gi * gg;
                float hh = go * ftanh(c2);
                h2buf[nxt][g2id] = hh;
                ring[g2id * 65 + ((t - 1) & 63)] = hh;   // conflict-free (stride 65)
            }
        }
        __syncthreads();   // B2: h(t) visible for next iter

        // ---- batched projection: 64 outputs, wave 0 only, every 64 steps ----
        // Other waves proceed into iter t+1; they can't write ring/g before
        // wave 0 reaches B1(t+1), so these reads are race-free.
        if ((t & 63) == 0 && t >= 64 && tid < 64) {
            float p = bpv;
            #pragma unroll
            for (int k = 0; k < 30; ++k)
                p += wpls[k] * ring[k * 65 + tid];       // conflict-free column read
            outb[t - 64 + tid] = p;
        }
    }
}

extern "C" void kernel_launch(void* const* d_in, const int* in_sizes, int n_in,
                              void* d_out, int out_size, void* d_ws, size_t ws_size,
                              hipStream_t stream) {
    const float* x    = (const float*)d_in[0];
    const float* Wih1 = (const float*)d_in[1];
    const float* Whh1 = (const float*)d_in[2];
    const float* bih1 = (const float*)d_in[3];
    const float* bhh1 = (const float*)d_in[4];
    const float* Wih2 = (const float*)d_in[5];
    const float* Whh2 = (const float*)d_in[6];
    const float* bih2 = (const float*)d_in[7];
    const float* bhh2 = (const float*)d_in[8];
    const float* Wp   = (const float*)d_in[9];
    const float* bp   = (const float*)d_in[10];

    int B = in_sizes[0] / (T_LEN * D_IN);   // 512

    lstm_fused<<<B, NTHREADS, 0, stream>>>(x, Wih1, Whh1, bih1, bhh1,
                                           Wih2, Whh2, bih2, bhh2,
                                           Wp, bp, (float*)d_out);
}

// Round 3
// 1892.891 us; speedup vs baseline: 1.9189x; 1.5609x over previous
//
#include <hip/hip_runtime.h>

#define T_LEN 2048
#define D_IN  15
#define XCH   128
#define NTH   768

// region layout (float offsets); one region per sequence, 2 per block
#define OXF   0          // x chunk [128][16]
#define OH1   2048       // h1 [64] (60 + 4 zero pad)
#define OH2   2112       // h2 [32] (30 + 2 zero pad)
#define OG1   2144       // gates1 [240]
#define OG2   2384       // gates2 [120]
#define ORNG  2504       // ring [30*65]
#define RSZ   4480       // region floats (17920 B)
#define SEQB  (RSZ * 4)  // byte delta seq0 -> seq1

__device__ __forceinline__ float sig2(float x2) {  // 1/(1+2^x2)
    float e = __builtin_amdgcn_exp2f(x2);
    return __builtin_amdgcn_rcpf(1.0f + e);
}
__device__ __forceinline__ float ftanh_(float x) {
    float e = __builtin_amdgcn_exp2f(x * 2.8853900817779268f);
    return 1.0f - 2.0f * __builtin_amdgcn_rcpf(e + 1.0f);
}

__global__ __launch_bounds__(NTH, 1) void lstm_fused(
    const float* __restrict__ x,
    const float* __restrict__ Wih1, const float* __restrict__ Whh1,
    const float* __restrict__ bih1, const float* __restrict__ bhh1,
    const float* __restrict__ Wih2, const float* __restrict__ Whh2,
    const float* __restrict__ bih2, const float* __restrict__ bhh2,
    const float* __restrict__ Wp,   const float* __restrict__ bp,
    float* __restrict__ out)
{
    __shared__ __align__(16) float lds[2 * RSZ];   // 35840 B
    __shared__ float wpls[32];

    const int tid  = threadIdx.x;
    const int b    = blockIdx.x;
    const char* ldsb = (const char*)lds;

    const bool isL1 = (tid < 480);                 // waves 0-7 (7 partial)
    const bool isL2 = (tid >= 512 && tid < 752);   // waves 8-11 (11 partial)
    const int  half = tid & 1;

    float4 w[12];
    unsigned off[12];
    #pragma unroll
    for (int k = 0; k < 12; ++k) { w[k] = make_float4(0.f,0.f,0.f,0.f); off[k] = OH1*4; }

    float bias = 0.f;
    float kneg = -1.4426950408889634f, mm = 1.f, cc = 0.f;  // act = mm*sig2(v*kneg)+cc
    float c_state = 0.f;

    if (isL1) {
        const int g = tid >> 1;
        const float* wh = Whh1 + g * 60;           // 240B stride, 16B-aligned
        if (half == 0) {
            const float* wi = Wih1 + g * D_IN;     // 15 floats, scalar loads
            w[0] = make_float4(wi[0],  wi[1],  wi[2],  wi[3]);
            w[1] = make_float4(wi[4],  wi[5],  wi[6],  wi[7]);
            w[2] = make_float4(wi[8],  wi[9],  wi[10], wi[11]);
            w[3] = make_float4(wi[12], wi[13], wi[14], 0.f);
            #pragma unroll
            for (int k = 0; k < 6; ++k) w[4 + k] = *(const float4*)(wh + 4 * k);   // h[0..23]
            off[0] = OXF*4 + 0;  off[1] = OXF*4 + 16;
            off[2] = OXF*4 + 32; off[3] = OXF*4 + 48;          // x f4 0..3 (dynamic)
            #pragma unroll
            for (int k = 4; k < 10; ++k) off[k] = OH1*4 + (k - 4) * 16;            // h f4 0..5
        } else {
            #pragma unroll
            for (int k = 0; k < 4; ++k) w[k] = *(const float4*)(wh + 24 + 4 * k);  // h[24..39]
            #pragma unroll
            for (int k = 4; k < 9; ++k) w[k] = *(const float4*)(wh + 24 + 4 * k);  // h[40..59]
            w[9] = make_float4(0.f,0.f,0.f,0.f);                                   // h[60..63] pad
            #pragma unroll
            for (int k = 0; k < 4; ++k)  off[k] = OH1*4 + (6 + k) * 16;            // h f4 6..9
            #pragma unroll
            for (int k = 4; k < 10; ++k) off[k] = OH1*4 + (6 + k) * 16;            // h f4 10..15
        }
        bias = bih1[g] + bhh1[g];
        if (g >= 120 && g < 180) { kneg = -2.8853900817779268f; mm = 2.f; cc = -1.f; }
    } else if (isL2) {
        const int i = tid - 512;
        const int g = i >> 1;
        const float4* wa = (const float4*)(Wih2 + g * 60);     // 240B stride, aligned
        if (half == 0) {
            #pragma unroll
            for (int k = 0; k < 12; ++k) { w[k] = wa[k]; off[k] = OH1*4 + k * 16; } // h1[0..47]
        } else {
            w[0] = wa[12]; w[1] = wa[13]; w[2] = wa[14];       // h1[48..59]
            w[3] = make_float4(0.f,0.f,0.f,0.f);               // h1[60..63] pad
            const float* wh = Whh2 + g * 30;                   // scalar loads (alignment)
            w[4]  = make_float4(wh[0],  wh[1],  wh[2],  wh[3]);
            w[5]  = make_float4(wh[4],  wh[5],  wh[6],  wh[7]);
            w[6]  = make_float4(wh[8],  wh[9],  wh[10], wh[11]);
            w[7]  = make_float4(wh[12], wh[13], wh[14], wh[15]);
            w[8]  = make_float4(wh[16], wh[17], wh[18], wh[19]);
            w[9]  = make_float4(wh[20], wh[21], wh[22], wh[23]);
            w[10] = make_float4(wh[24], wh[25], wh[26], wh[27]);
            w[11] = make_float4(wh[28], wh[29], 0.f, 0.f);     // h2[30..31] pad
            #pragma unroll
            for (int k = 0; k < 4; ++k)  off[k] = OH1*4 + (12 + k) * 16;  // h1 f4 12..15
            #pragma unroll
            for (int k = 4; k < 12; ++k) off[k] = OH2*4 + (k - 4) * 16;   // h2 f4 0..7
        }
        bias = bih2[g] + bhh2[g];
        if (g >= 60 && g < 90) { kneg = -2.8853900817779268f; mm = 2.f; cc = -1.f; }
    }

    // constants for per-chunk reset of the 4 dynamic slots
    const unsigned offc0 = off[0], offc1 = off[1], offc2 = off[2], offc3 = off[3];
    const unsigned xadv  = (isL1 && half == 0) ? 64u : 0u;

    // zero recurrent state + pads (LDS is undefined at start)
    if (tid < 64)                { lds[OH1 + tid] = 0.f;      lds[RSZ + OH1 + tid] = 0.f; }
    if (tid >= 64 && tid < 96)   { lds[OH2 + tid - 64] = 0.f; lds[RSZ + OH2 + tid - 64] = 0.f; }
    if (tid < 30) wpls[tid] = Wp[tid];
    const float bpv = bp[0];
    __syncthreads();

    const float* xb = x + (size_t)b * 2 * T_LEN * D_IN;

    for (int t = 0; t <= T_LEN; ++t) {
        // ---- stage next 128 steps of x for both seqs (uniform branch) ----
        if ((t & (XCH - 1)) == 0 && t < T_LEN) {
            #pragma unroll
            for (int r = 0; r < 5; ++r) {
                int i   = tid + r * NTH;            // 0..3839 exact
                int s   = i / 1920;
                int rem = i - s * 1920;
                int tt  = rem / D_IN;
                int dd  = rem - tt * D_IN;
                lds[s * RSZ + OXF + tt * 16 + dd] =
                    xb[(size_t)s * T_LEN * D_IN + (size_t)t * D_IN + rem];
            }
            if (tid < 256) { int s = tid >> 7, tt = tid & 127; lds[s*RSZ + OXF + tt*16 + 15] = 0.f; }
            off[0] = offc0; off[1] = offc1; off[2] = offc2; off[3] = offc3;
            __syncthreads();
        }

        // ---------------- phase 1: gate pre-activations ----------------
        if (isL1 && t < T_LEN) {
            float a0x=0.f,a0y=0.f,a0z=0.f,a0w=0.f, a1x=0.f,a1y=0.f,a1z=0.f,a1w=0.f;
            #pragma unroll
            for (int k = 0; k < 10; ++k) {
                float4 v0 = *(const float4*)(ldsb + off[k]);
                float4 v1 = *(const float4*)(ldsb + off[k] + SEQB);
                a0x = fmaf(v0.x, w[k].x, a0x); a0y = fmaf(v0.y, w[k].y, a0y);
                a0z = fmaf(v0.z, w[k].z, a0z); a0w = fmaf(v0.w, w[k].w, a0w);
                a1x = fmaf(v1.x, w[k].x, a1x); a1y = fmaf(v1.y, w[k].y, a1y);
                a1z = fmaf(v1.z, w[k].z, a1z); a1w = fmaf(v1.w, w[k].w, a1w);
            }
            float p0 = (a0x + a0y) + (a0z + a0w);
            float p1 = (a1x + a1y) + (a1z + a1w);
            p0 += __shfl_xor(p0, 1);
            p1 += __shfl_xor(p1, 1);
            if (half == 0) {
                const int g = tid >> 1;
                lds[OG1 + g]       = mm * sig2((p0 + bias) * kneg) + cc;
                lds[RSZ + OG1 + g] = mm * sig2((p1 + bias) * kneg) + cc;
            }
            off[0] += xadv; off[1] += xadv; off[2] += xadv; off[3] += xadv;
        } else if (isL2 && t >= 1) {
            float a0x=0.f,a0y=0.f,a0z=0.f,a0w=0.f, a1x=0.f,a1y=0.f,a1z=0.f,a1w=0.f;
            #pragma unroll
            for (int k = 0; k < 12; ++k) {
                float4 v0 = *(const float4*)(ldsb + off[k]);
                float4 v1 = *(const float4*)(ldsb + off[k] + SEQB);
                a0x = fmaf(v0.x, w[k].x, a0x); a0y = fmaf(v0.y, w[k].y, a0y);
                a0z = fmaf(v0.z, w[k].z, a0z); a0w = fmaf(v0.w, w[k].w, a0w);
                a1x = fmaf(v1.x, w[k].x, a1x); a1y = fmaf(v1.y, w[k].y, a1y);
                a1z = fmaf(v1.z, w[k].z, a1z); a1w = fmaf(v1.w, w[k].w, a1w);
            }
            float p0 = (a0x + a0y) + (a0z + a0w);
            float p1 = (a1x + a1y) + (a1z + a1w);
            p0 += __shfl_xor(p0, 1);
            p1 += __shfl_xor(p1, 1);
            if (half == 0) {
                const int g = (tid - 512) >> 1;
                lds[OG2 + g]       = mm * sig2((p0 + bias) * kneg) + cc;
                lds[RSZ + OG2 + g] = mm * sig2((p1 + bias) * kneg) + cc;
            }
        }
        __syncthreads();   // B1: gates visible

        // ---------------- phase 2: state update ----------------
        if (tid < 120 && t < T_LEN) {
            const int s = (tid >= 60);
            const int u = tid - 60 * s;
            const float* g1 = lds + s * RSZ + OG1;
            float gi = g1[u], gf = g1[60 + u], gg = g1[120 + u], go = g1[180 + u];
            c_state = gf * c_state + gi * gg;
            lds[s * RSZ + OH1 + u] = go * ftanh_(c_state);
        } else if (tid >= 128 && tid < 188 && t >= 1) {
            const int v = tid - 128;
            const int s = (v >= 30);
            const int u = v - 30 * s;
            const float* g2 = lds + s * RSZ + OG2;
            float gi = g2[u], gf = g2[30 + u], gg = g2[60 + u], go = g2[90 + u];
            c_state = gf * c_state + gi * gg;
            float hh = go * ftanh_(c_state);
            lds[s * RSZ + OH2 + u] = hh;
            lds[s * RSZ + ORNG + u * 65 + ((t - 1) & 63)] = hh;
        }
        __syncthreads();   // B2: h(t) visible

        // ---- batched projection: 2 seqs x 64 outputs, every 64 steps ----
        // Safe: writers of ring/gates in iter t+1 are blocked by B1(t+1),
        // which these threads haven't reached yet.
        if ((t & 63) == 0 && t >= 64 && tid >= 256 && tid < 384) {
            const int j = tid - 256;
            const int s = j >> 6;
            const int col = j & 63;
            const float* rg = lds + s * RSZ + ORNG;
            float p = bpv;
            #pragma unroll
            for (int k = 0; k < 30; ++k) p = fmaf(wpls[k], rg[k * 65 + col], p);
            out[(size_t)(2 * b + s) * T_LEN + (t - 64) + col] = p;
        }
    }
}

extern "C" void kernel_launch(void* const* d_in, const int* in_sizes, int n_in,
                              void* d_out, int out_size, void* d_ws, size_t ws_size,
                              hipStream_t stream) {
    const float* x    = (const float*)d_in[0];
    const float* Wih1 = (const float*)d_in[1];
    const float* Whh1 = (const float*)d_in[2];
    const float* bih1 = (const float*)d_in[3];
    const float* bhh1 = (const float*)d_in[4];
    const float* Wih2 = (const float*)d_in[5];
    const float* Whh2 = (const float*)d_in[6];
    const float* bih2 = (const float*)d_in[7];
    const float* bhh2 = (const float*)d_in[8];
    const float* Wp   = (const float*)d_in[9];
    const float* bp   = (const float*)d_in[10];

    int B = in_sizes[0] / (T_LEN * D_IN);   // 512
    int grid = B / 2;                        // 2 sequences per block

    lstm_fused<<<grid, NTH, 0, stream>>>(x, Wih1, Whh1, bih1, bhh1,
                                         Wih2, Whh2, bih2, bhh2,
                                         Wp, bp, (float*)d_out);
}

// Round 5
// 1779.497 us; speedup vs baseline: 2.0412x; 1.0637x over previous
//
#include <hip/hip_runtime.h>

#define T_LEN 2048
#define D_IN  15
#define NTH   768

// per-seq region float offsets
#define OX    0                 // x chunk [128][16] (col 15 zero pad)
#define OHS   2048              // hs[2][128]: h1=0..59, h2=60..89, pad 90..127
#define ORG   2304              // ring [30][130] (h2 history, depth 128 + 2 pad)
#define RSZF  6208              // region floats
#define RSZB  (RSZF * 4)
#define OXB   (OX * 4)
#define OHSB  (OHS * 4)
#define ORGB  (ORG * 4)

__device__ __forceinline__ float sig2(float x2) {   // 1/(1+2^x2)
    return __builtin_amdgcn_rcpf(1.0f + __builtin_amdgcn_exp2f(x2));
}
__device__ __forceinline__ float ftanh_(float x) {
    return 1.0f - 2.0f * __builtin_amdgcn_rcpf(
        __builtin_amdgcn_exp2f(x * 2.8853900817779268f) + 1.0f);
}

// one ds_read_b128 feeding 16 FMAs (4 gate rows x 4 components)
#define GSTEP(OFS, kk) do {                                         \
    float4 v = *(const float4*)(ldsb + (OFS));                      \
    ac0.x = fmaf(v.x, w[0][kk].x, ac0.x);                           \
    ac0.y = fmaf(v.y, w[0][kk].y, ac0.y);                           \
    ac0.z = fmaf(v.z, w[0][kk].z, ac0.z);                           \
    ac0.w = fmaf(v.w, w[0][kk].w, ac0.w);                           \
    ac1.x = fmaf(v.x, w[1][kk].x, ac1.x);                           \
    ac1.y = fmaf(v.y, w[1][kk].y, ac1.y);                           \
    ac1.z = fmaf(v.z, w[1][kk].z, ac1.z);                           \
    ac1.w = fmaf(v.w, w[1][kk].w, ac1.w);                           \
    ac2.x = fmaf(v.x, w[2][kk].x, ac2.x);                           \
    ac2.y = fmaf(v.y, w[2][kk].y, ac2.y);                           \
    ac2.z = fmaf(v.z, w[2][kk].z, ac2.z);                           \
    ac2.w = fmaf(v.w, w[2][kk].w, ac2.w);                           \
    ac3.x = fmaf(v.x, w[3][kk].x, ac3.x);                           \
    ac3.y = fmaf(v.y, w[3][kk].y, ac3.y);                           \
    ac3.z = fmaf(v.z, w[3][kk].z, ac3.z);                           \
    ac3.w = fmaf(v.w, w[3][kk].w, ac3.w);                           \
} while (0)

// Reduce-scatter across the quad with __shfl_xor (R3-proven primitive):
// lane q ends with S = full preactivation of gate q; then activate and
// gather f,g,o onto the q0 lane. P(L,g) = lane L's partial of gate g.
#define COMBINE_ACT()                                               \
    float p0 = (ac0.x + ac0.y) + (ac0.z + ac0.w);                   \
    float p1 = (ac1.x + ac1.y) + (ac1.z + ac1.w);                   \
    float p2 = (ac2.x + ac2.y) + (ac2.z + ac2.w);                   \
    float p3 = (ac3.x + ac3.y) + (ac3.z + ac3.w);                   \
    float ps = (q & 2) ? ((q & 1) ? p3 : p2) : ((q & 1) ? p1 : p0); /* p[q]   */ \
    float pa = (q & 2) ? ((q & 1) ? p2 : p3) : ((q & 1) ? p0 : p1); /* p[q^1] */ \
    float pc = (q & 2) ? ((q & 1) ? p1 : p0) : ((q & 1) ? p3 : p2); /* p[q^2] */ \
    float pb = (q & 2) ? ((q & 1) ? p0 : p1) : ((q & 1) ? p2 : p3); /* p[q^3] */ \
    float A = ps + __shfl_xor(pa, 1);   /* gate q   over quarters {q,q^1} */ \
    float B = pc + __shfl_xor(pb, 1);   /* gate q^2 over quarters {q,q^1} */ \
    float S = A + __shfl_xor(B, 2);     /* gate q, all quarters */          \
    float a  = fmaf(mm, sig2((S + bias) * kneg), cc);               \
    float af = __shfl_xor(a, 1);   /* q0 <- f */                    \
    float ag = __shfl_xor(a, 2);   /* q0 <- g */                    \
    float ao = __shfl_xor(af, 2);  /* q0 <- o */

__global__ __launch_bounds__(NTH, 3) void lstm_fused(
    const float* __restrict__ x,
    const float* __restrict__ Wih1, const float* __restrict__ Whh1,
    const float* __restrict__ bih1, const float* __restrict__ bhh1,
    const float* __restrict__ Wih2, const float* __restrict__ Whh2,
    const float* __restrict__ bih2, const float* __restrict__ bhh2,
    const float* __restrict__ Wp,   const float* __restrict__ bp,
    float* __restrict__ out)
{
    __shared__ __align__(16) float lds[2 * RSZF];   // 49664 B
    __shared__ float wpls[32];

    const int tid = threadIdx.x;
    const int b   = blockIdx.x;
    const char* ldsb = (const char*)lds;

    const bool isL1 = (tid < 480);                  // waves 0-7 (7 half idle)
    const bool isL2 = (tid >= 512 && tid < 752);    // waves 8-11

    int u = 0, s = 0, q = 0;
    if (isL1)      { u = tid >> 3;      s = (tid >> 2) & 1;          q = tid & 3; }
    else if (isL2) { int l = tid - 512; u = l >> 3; s = (l >> 2) & 1; q = l & 3; }
    const unsigned regB = (unsigned)s * RSZB;

    float4 w[4][6];
    #pragma unroll
    for (int g = 0; g < 4; ++g)
        #pragma unroll
        for (int k = 0; k < 6; ++k) w[g][k] = make_float4(0.f, 0.f, 0.f, 0.f);

    unsigned b0 = 0, b1 = 0, b2 = 0, b3 = 0, b4 = 0, b5 = 0, wb = 0, ringb = 0;
    float bias = 0.f, kneg = -1.4426950408889634f, mm = 1.f, cc = 0.f;
    float cst = 0.f;

    if (isL1) {
        // lane owns: quarter q of padded operand [x(16)|h1(60)|pad(4)],
        // all 4 gate rows (i,f,g,o) of unit u, sequence s.
        #pragma unroll
        for (int g = 0; g < 4; ++g) {
            const int r = g * 60 + u;
            #pragma unroll
            for (int k = 0; k < 5; ++k) {
                float e0[4];
                #pragma unroll
                for (int e = 0; e < 4; ++e) {
                    int j = q * 20 + k * 4 + e;
                    float val;
                    if (j < 15)      val = Wih1[r * 15 + j];
                    else if (j < 16) val = 0.f;                    // x pad
                    else if (j < 76) val = Whh1[r * 60 + (j - 16)];
                    else             val = 0.f;                    // h1 pad
                    e0[e] = val;
                }
                w[g][k] = make_float4(e0[0], e0[1], e0[2], e0[3]);
            }
        }
        bias = bih1[q * 60 + u] + bhh1[q * 60 + u];
        if (q == 2) { kneg = -2.8853900817779268f; mm = 2.f; cc = -1.f; }
        if (q == 0) {
            b0 = regB + OXB + 0;  b1 = regB + OXB + 16;
            b2 = regB + OXB + 32; b3 = regB + OXB + 48;   // x f4s (+xrow)
            b4 = regB + OHSB + 0;                          // h1[0..3] (+rb)
        } else {
            unsigned hb = regB + OHSB + (unsigned)(q * 80 - 64);
            b0 = hb; b1 = hb + 16; b2 = hb + 32; b3 = hb + 48;  // (+rb)
            b4 = hb + 64;                                        // (+rb)
        }
        wb = regB + OHSB + (unsigned)u * 4;
    } else if (isL2) {
        // operand = hs[0..95]: h1(60)|h2(30)|pad(6); quarter = 24 elems
        #pragma unroll
        for (int g = 0; g < 4; ++g) {
            const int r = g * 30 + u;
            #pragma unroll
            for (int k = 0; k < 6; ++k) {
                float e0[4];
                #pragma unroll
                for (int e = 0; e < 4; ++e) {
                    int j = q * 24 + k * 4 + e;
                    float val;
                    if (j < 60)      val = Wih2[r * 60 + j];
                    else if (j < 90) val = Whh2[r * 30 + (j - 60)];
                    else             val = 0.f;                   // pad
                    e0[e] = val;
                }
                w[g][k] = make_float4(e0[0], e0[1], e0[2], e0[3]);
            }
        }
        bias = bih2[q * 30 + u] + bhh2[q * 30 + u];
        if (q == 2) { kneg = -2.8853900817779268f; mm = 2.f; cc = -1.f; }
        unsigned hb = regB + OHSB + (unsigned)(q * 96);
        b0 = hb;      b1 = hb + 16; b2 = hb + 32;
        b3 = hb + 48; b4 = hb + 64; b5 = hb + 80;          // (+rb)
        wb    = regB + OHSB + (unsigned)(60 + u) * 4;
        ringb = regB + ORGB + (unsigned)u * 520;
    }

    // init: hs (both buffers incl pads) = 0; x pad column = 0; Wp staged
    if (tid < 512) { int ss = tid >> 8; int i = tid & 255; lds[ss * RSZF + OHS + i] = 0.f; }
    else           { int i = tid - 512; int ss = i >> 7;   lds[ss * RSZF + OX + (i & 127) * 16 + 15] = 0.f; }
    if (tid < 30) wpls[tid] = Wp[tid];
    const float bpv = bp[0];
    __syncthreads();

    const float* xb = x + (size_t)b * 2 * T_LEN * D_IN;

    for (int t = 0; t <= T_LEN; ++t) {
        // ---- stage next 128 timesteps of x for both seqs (uniform) ----
        if ((t & 127) == 0 && t < T_LEN) {
            #pragma unroll
            for (int r5 = 0; r5 < 5; ++r5) {
                int i   = tid + r5 * NTH;        // 0..3839 exact
                int ss  = i / 1920;
                int rem = i - ss * 1920;
                int tt  = rem / 15;
                int dd  = rem - tt * 15;
                lds[ss * RSZF + OX + tt * 16 + dd] =
                    xb[(size_t)ss * T_LEN * D_IN + (size_t)t * D_IN + rem];
            }
            __syncthreads();
        }

        const unsigned rb   = (unsigned)(t & 1) << 9;   // read-buffer byte off
        const unsigned wbuf = rb ^ 512u;                // write-buffer byte off

        // ------------- gate compute + in-quad state update -------------
        if (isL1 && t < T_LEN) {
            const unsigned dyn = (q == 0) ? ((unsigned)(t & 127) << 6) : rb;
            float4 ac0 = make_float4(0,0,0,0), ac1 = make_float4(0,0,0,0),
                   ac2 = make_float4(0,0,0,0), ac3 = make_float4(0,0,0,0);
            GSTEP(b0 + dyn, 0); GSTEP(b1 + dyn, 1); GSTEP(b2 + dyn, 2);
            GSTEP(b3 + dyn, 3); GSTEP(b4 + rb, 4);
            COMBINE_ACT();
            if (q == 0) {
                cst = fmaf(af, cst, a * ag);
                *(float*)((char*)lds + (wb + wbuf)) = ao * ftanh_(cst);
            }
        } else if (isL2 && t >= 1) {
            float4 ac0 = make_float4(0,0,0,0), ac1 = make_float4(0,0,0,0),
                   ac2 = make_float4(0,0,0,0), ac3 = make_float4(0,0,0,0);
            GSTEP(b0 + rb, 0); GSTEP(b1 + rb, 1); GSTEP(b2 + rb, 2);
            GSTEP(b3 + rb, 3); GSTEP(b4 + rb, 4); GSTEP(b5 + rb, 5);
            COMBINE_ACT();
            if (q == 0) {
                cst = fmaf(af, cst, a * ag);
                float hv = ao * ftanh_(cst);
                *(float*)((char*)lds + (wb + wbuf)) = hv;
                *(float*)((char*)lds + (ringb + (unsigned)(((t - 1) & 127) << 2))) = hv;
            }
        }
        __syncthreads();   // h(t)/h2(t-1)/ring visible

        // ---- batched projection: 2 seqs x 64 outputs every 64 steps ----
        // ring depth 128: writers in iters t+1..t+64 touch the other half;
        // skew >1 iter impossible (barriers require these lanes).
        if ((t & 63) == 0 && t >= 64 && tid < 128) {
            const int ss  = tid >> 6;
            const int col = tid & 63;
            const int sl  = ((t - 64) & 64) + col;
            const float* rg = lds + ss * RSZF + ORG;
            float p = bpv;
            #pragma unroll
            for (int k = 0; k < 30; ++k) p = fmaf(wpls[k], rg[k * 130 + sl], p);
            out[(size_t)(2 * b + ss) * T_LEN + (t - 64) + col] = p;
        }
    }
}

extern "C" void kernel_launch(void* const* d_in, const int* in_sizes, int n_in,
                              void* d_out, int out_size, void* d_ws, size_t ws_size,
                              hipStream_t stream) {
    const float* x    = (const float*)d_in[0];
    const float* Wih1 = (const float*)d_in[1];
    const float* Whh1 = (const float*)d_in[2];
    const float* bih1 = (const float*)d_in[3];
    const float* bhh1 = (const float*)d_in[4];
    const float* Wih2 = (const float*)d_in[5];
    const float* Whh2 = (const float*)d_in[6];
    const float* bih2 = (const float*)d_in[7];
    const float* bhh2 = (const float*)d_in[8];
    const float* Wp   = (const float*)d_in[9];
    const float* bp   = (const float*)d_in[10];

    int B = in_sizes[0] / (T_LEN * D_IN);   // 512
    int grid = B / 2;                        // 2 sequences per block = 256 = #CUs

    lstm_fused<<<grid, NTH, 0, stream>>>(x, Wih1, Whh1, bih1, bhh1,
                                         Wih2, Whh2, bih2, bhh2,
                                         Wp, bp, (float*)d_out);
}